// Round 7
// baseline (768.914 us; speedup 1.0000x reference)
//
#include <hip/hip_runtime.h>
#include <hip/hip_fp16.h>

#define N_PTS 524288
#define NBUCK 1024
#define SBLK 1024               // points per sort block
#define NSBLK (N_PTS / SBLK)    // 512

typedef __attribute__((ext_vector_type(8))) short bf16x8;
typedef __attribute__((ext_vector_type(4))) short bf16x4;
typedef __attribute__((ext_vector_type(4))) float f32x4;

// float -> bf16 (round-to-nearest-even), bit pattern in ushort
__device__ __forceinline__ unsigned short f2bf(float f) {
    unsigned u = __builtin_bit_cast(unsigned, f);
    u = (u + 0x7FFFu + ((u >> 16) & 1u)) >> 16;
    return (unsigned short)u;
}

__device__ __forceinline__ float encf(float v, float f) {
    float t = v * f;
    return 2.0f * (t - floorf(t)) - 1.0f;   // jnp: 2*(f*x % 1) - 1
}

// spatial bucket key: top bits of the g3 (256^3, freq-8) integer coords.
// 10 bits: (iz>>4)<<6 | (iy>>5)<<3 | (ix>>5). Must be identical in hist/scatter.
__device__ __forceinline__ int bucket_of(float px, float py, float pz) {
    float cx = (encf(px, 8.f) + 1.0f) * 127.5f;
    float cy = (encf(py, 8.f) + 1.0f) * 127.5f;
    float cz = (encf(pz, 8.f) + 1.0f) * 127.5f;
    int ix = min(max((int)floorf(cx), 0), 255);
    int iy = min(max((int)floorf(cy), 0), 255);
    int iz = min(max((int)floorf(cz), 0), 255);
    return ((iz >> 4) << 6) | ((iy >> 5) << 3) | (ix >> 5);
}

// ---------------- sort pass kernels (ZERO global atomics) ----------------
// pass 1: per-block LDS histogram -> hist2d[blk][NBUCK] (coalesced)
__global__ __launch_bounds__(256) void hist2_kernel(const float* __restrict__ x,
                                                    unsigned* __restrict__ hist2d) {
    __shared__ unsigned lh[NBUCK];
    int t = threadIdx.x;
    int blk = blockIdx.x;
#pragma unroll
    for (int i = 0; i < 4; ++i) lh[t + i * 256] = 0u;
    __syncthreads();
#pragma unroll
    for (int i = 0; i < 4; ++i) {
        int gid = blk * SBLK + i * 256 + t;
        atomicAdd(&lh[bucket_of(x[3 * gid], x[3 * gid + 1], x[3 * gid + 2])], 1u);
    }
    __syncthreads();
#pragma unroll
    for (int i = 0; i < 4; ++i)
        hist2d[(size_t)blk * NBUCK + t + i * 256] = lh[t + i * 256];
}

// pass 2: per-bucket scan over the 512 block counts (1 wave per bucket).
// start2d[blk][j] = # of bucket-j points in blocks < blk; totals[j] = count.
__global__ __launch_bounds__(64) void scanb_kernel(const unsigned* __restrict__ hist2d,
                                                   unsigned* __restrict__ start2d,
                                                   unsigned* __restrict__ totals) {
    int j = blockIdx.x;         // bucket
    int lane = threadIdx.x;     // 0..63, covers blocks [lane*8, lane*8+8)
    int b0 = lane * 8;
    unsigned c[8];
#pragma unroll
    for (int k = 0; k < 8; ++k) c[k] = hist2d[(size_t)(b0 + k) * NBUCK + j];
    unsigned s = 0;
#pragma unroll
    for (int k = 0; k < 8; ++k) s += c[k];
    // wave-exclusive scan of s across 64 lanes
    unsigned v = s;
    for (int off = 1; off < 64; off <<= 1) {
        unsigned u = __shfl_up(v, off, 64);
        if (lane >= off) v += u;
    }
    unsigned run = v - s;       // exclusive prefix
#pragma unroll
    for (int k = 0; k < 8; ++k) {
        start2d[(size_t)(b0 + k) * NBUCK + j] = run;
        run += c[k];
    }
    if (lane == 63) totals[j] = run;
}

// pass 3: exclusive scan of bucket totals -> bucketBase
__global__ __launch_bounds__(1024) void scan_kernel(const unsigned* __restrict__ totals,
                                                    unsigned* __restrict__ bucketBase) {
    __shared__ unsigned s[NBUCK];
    int t = threadIdx.x;
    unsigned mine = totals[t];
    s[t] = mine;
    __syncthreads();
    for (int off = 1; off < NBUCK; off <<= 1) {
        unsigned v = (t >= off) ? s[t - off] : 0u;
        __syncthreads();
        s[t] += v;
        __syncthreads();
    }
    bucketBase[t] = s[t] - mine;   // exclusive prefix
}

// pass 4: deterministic scatter; local rank via LDS atomics only.
__global__ __launch_bounds__(256) void scatter2_kernel(
    const float* __restrict__ x,
    const unsigned* __restrict__ start2d,
    const unsigned* __restrict__ bucketBase,
    float4* __restrict__ rec, int* __restrict__ invPos) {
    __shared__ unsigned lc[NBUCK];
    int t = threadIdx.x;
    int blk = blockIdx.x;
#pragma unroll
    for (int i = 0; i < 4; ++i) lc[t + i * 256] = 0u;
    __syncthreads();
#pragma unroll
    for (int i = 0; i < 4; ++i) {
        int gid = blk * SBLK + i * 256 + t;
        float px = x[3 * gid], py = x[3 * gid + 1], pz = x[3 * gid + 2];
        int b = bucket_of(px, py, pz);
        unsigned lrank = atomicAdd(&lc[b], 1u);   // LDS atomic: cheap
        unsigned pos = bucketBase[b] + start2d[(size_t)blk * NBUCK + b] + lrank;
        rec[pos] = make_float4(px, py, pz, 0.0f);
        invPos[gid] = (int)pos;
    }
}

// ---------------- channel-interleave to fp16: [4][R^3] -> [R^3][4] ----------------
template <int R>
__global__ __launch_bounds__(256) void ileaveh_kernel(const float* __restrict__ g,
                                                      unsigned short* __restrict__ gi) {
    constexpr int V = R * R * R;
    int idx = blockIdx.x * 256 + threadIdx.x;
    ushort4 v;
    v.x = __half_as_ushort(__float2half(g[idx]));
    v.y = __half_as_ushort(__float2half(g[idx + V]));
    v.z = __half_as_ushort(__float2half(g[idx + 2 * V]));
    v.w = __half_as_ushort(__float2half(g[idx + 3 * V]));
    *(ushort4*)(&gi[(size_t)idx * 4]) = v;
}

__device__ __forceinline__ float4 h4f(const unsigned short* p) {
    uint2 u = *(const uint2*)p;
    float4 r;
    r.x = __half2float(__ushort_as_half((unsigned short)(u.x & 0xffffu)));
    r.y = __half2float(__ushort_as_half((unsigned short)(u.x >> 16)));
    r.z = __half2float(__ushort_as_half((unsigned short)(u.y & 0xffffu)));
    r.w = __half2float(__ushort_as_half((unsigned short)(u.y >> 16)));
    return r;
}

// trilerp over fp16 channel-interleaved grid: one 8B load per corner
template <int R>
__device__ __forceinline__ float4 trilerp4h(const unsigned short* __restrict__ gi,
                                            float px, float py, float pz) {
    constexpr float S = 0.5f * (float)(R - 1);
    float cx = (px + 1.0f) * S;
    float cy = (py + 1.0f) * S;
    float cz = (pz + 1.0f) * S;
    float fx0 = floorf(cx), fy0 = floorf(cy), fz0 = floorf(cz);
    float fx = cx - fx0, fy = cy - fy0, fz = cz - fz0;
    int ix0 = min(max((int)fx0, 0), R - 1);
    int iy0 = min(max((int)fy0, 0), R - 1);
    int iz0 = min(max((int)fz0, 0), R - 1);
    int dx = (ix0 < R - 1) ? 4 : 0;           // offsets in ushorts (4 ch)
    int dy = (iy0 < R - 1) ? 4 * R : 0;
    int dz = (iz0 < R - 1) ? 4 * R * R : 0;
    const unsigned short* p = gi + 4 * ((size_t)iz0 * (R * R) + iy0 * R + ix0);

    float4 v000 = h4f(p);
    float4 v001 = h4f(p + dx);
    float4 v010 = h4f(p + dy);
    float4 v011 = h4f(p + dy + dx);
    float4 v100 = h4f(p + dz);
    float4 v101 = h4f(p + dz + dx);
    float4 v110 = h4f(p + dz + dy);
    float4 v111 = h4f(p + dz + dy + dx);

    float gx0 = 1.0f - fx, gy0 = 1.0f - fy, gz0 = 1.0f - fz;
    float w00 = gz0 * gy0, w01 = gz0 * fy, w10 = fz * gy0, w11 = fz * fy;
    float w000 = w00 * gx0, w001 = w00 * fx;
    float w010 = w01 * gx0, w011 = w01 * fx;
    float w100 = w10 * gx0, w101 = w10 * fx;
    float w110 = w11 * gx0, w111 = w11 * fx;

    float4 r;
    r.x = v000.x * w000 + v001.x * w001 + v010.x * w010 + v011.x * w011 +
          v100.x * w100 + v101.x * w101 + v110.x * w110 + v111.x * w111;
    r.y = v000.y * w000 + v001.y * w001 + v010.y * w010 + v011.y * w011 +
          v100.y * w100 + v101.y * w101 + v110.y * w110 + v111.y * w111;
    r.z = v000.z * w000 + v001.z * w001 + v010.z * w010 + v011.z * w011 +
          v100.z * w100 + v101.z * w101 + v110.z * w110 + v111.z * w111;
    r.w = v000.w * w000 + v001.w * w001 + v010.w * w010 + v011.w * w011 +
          v100.w * w100 + v101.w * w101 + v110.w * w110 + v111.w * w111;
    return r;
}

// strided (original-layout fp32) trilerp — fallback path only
template <int R>
__device__ __forceinline__ float4 trilerp4s(const float* __restrict__ g,
                                            float px, float py, float pz) {
    constexpr float S = 0.5f * (float)(R - 1);
    float cx = (px + 1.0f) * S;
    float cy = (py + 1.0f) * S;
    float cz = (pz + 1.0f) * S;
    float fx0 = floorf(cx), fy0 = floorf(cy), fz0 = floorf(cz);
    float fx = cx - fx0, fy = cy - fy0, fz = cz - fz0;
    int ix0 = min(max((int)fx0, 0), R - 1);
    int iy0 = min(max((int)fy0, 0), R - 1);
    int iz0 = min(max((int)fz0, 0), R - 1);
    int dx = (ix0 < R - 1) ? 1 : 0;
    int dy = (iy0 < R - 1) ? R : 0;
    int dz = (iz0 < R - 1) ? R * R : 0;
    int base = iz0 * (R * R) + iy0 * R + ix0;

    float gx0 = 1.0f - fx, gy0 = 1.0f - fy, gz0 = 1.0f - fz;
    float w00 = gz0 * gy0, w01 = gz0 * fy, w10 = fz * gy0, w11 = fz * fy;
    float w000 = w00 * gx0, w001 = w00 * fx;
    float w010 = w01 * gx0, w011 = w01 * fx;
    float w100 = w10 * gx0, w101 = w10 * fx;
    float w110 = w11 * gx0, w111 = w11 * fx;

    float4 out;
    float r[4];
#pragma unroll
    for (int c = 0; c < 4; ++c) {
        const float* gc = g + (size_t)c * (R * R * R);
        r[c] = gc[base] * w000 + gc[base + dx] * w001 + gc[base + dy] * w010 +
               gc[base + dy + dx] * w011 + gc[base + dz] * w100 +
               gc[base + dz + dx] * w101 + gc[base + dz + dy] * w110 +
               gc[base + dz + dy + dx] * w111;
    }
    out.x = r[0]; out.y = r[1]; out.z = r[2]; out.w = r[3];
    return out;
}

// shared feature math: grids -> 16 bf16 feature shorts at feats[i*16]
__device__ __forceinline__ void feat_core(
    float px, float py, float pz,
    const unsigned short* __restrict__ g0i, const unsigned short* __restrict__ g1i,
    const unsigned short* __restrict__ g2i, const unsigned short* __restrict__ g3i,
    const unsigned short* __restrict__ coefi,
    unsigned short* __restrict__ feats, size_t i) {
    float4 cf = trilerp4h<64>(coefi, px, py, pz);
    float4 t0 = trilerp4h<32>(g0i, encf(px, 1.f), encf(py, 1.f), encf(pz, 1.f));
    float4 t1 = trilerp4h<64>(g1i, encf(px, 2.f), encf(py, 2.f), encf(pz, 2.f));
    float4 t2 = trilerp4h<128>(g2i, encf(px, 4.f), encf(py, 4.f), encf(pz, 4.f));
    float4 t3 = trilerp4h<256>(g3i, encf(px, 8.f), encf(py, 8.f), encf(pz, 8.f));

    float o[16];
    o[0] = t0.x * cf.x; o[1] = t0.y * cf.x; o[2] = t0.z * cf.x; o[3] = t0.w * cf.x;
    o[4] = t1.x * cf.y; o[5] = t1.y * cf.y; o[6] = t1.z * cf.y; o[7] = t1.w * cf.y;
    o[8] = t2.x * cf.z; o[9] = t2.y * cf.z; o[10] = t2.z * cf.z; o[11] = t2.w * cf.z;
    o[12] = t3.x * cf.w; o[13] = t3.y * cf.w; o[14] = t3.z * cf.w; o[15] = t3.w * cf.w;

    bf16x8 lo, hi;
#pragma unroll
    for (int j = 0; j < 8; ++j) {
        lo[j] = (short)f2bf(o[j]);
        hi[j] = (short)f2bf(o[8 + j]);
    }
    bf16x8* dst = (bf16x8*)(feats + i * 16);
    dst[0] = lo;
    dst[1] = hi;
}

// ---------------- kernel 1a: features from SORTED records, 2 pts/thread ----------
// Two independent trilerp chains per thread double outstanding loads (the kernel
// is memory-latency-bound: VALUBusy ~5%, not BW-bound).
__global__ __launch_bounds__(256) void feat_sorted_kernel(
    const float4* __restrict__ rec,
    const unsigned short* __restrict__ g0i, const unsigned short* __restrict__ g1i,
    const unsigned short* __restrict__ g2i, const unsigned short* __restrict__ g3i,
    const unsigned short* __restrict__ coefi,
    unsigned short* __restrict__ feats) {
    int i0 = (blockIdx.x * 256 + threadIdx.x) * 2;
    float4 r0 = rec[i0];
    float4 r1 = rec[i0 + 1];
    feat_core(r0.x, r0.y, r0.z, g0i, g1i, g2i, g3i, coefi, feats, (size_t)i0);
    feat_core(r1.x, r1.y, r1.z, g0i, g1i, g2i, g3i, coefi, feats, (size_t)i0 + 1);
}

// ---------------- kernel 1b: features in original order (no sort) ----------------
__global__ __launch_bounds__(256) void feat_i_kernel(
    const float* __restrict__ x,
    const unsigned short* __restrict__ g0i, const unsigned short* __restrict__ g1i,
    const unsigned short* __restrict__ g2i, const unsigned short* __restrict__ g3i,
    const unsigned short* __restrict__ coefi,
    unsigned short* __restrict__ feats) {
    int i = blockIdx.x * 256 + threadIdx.x;
    feat_core(x[3 * i], x[3 * i + 1], x[3 * i + 2], g0i, g1i, g2i, g3i, coefi,
              feats, (size_t)i);
}

// fallback (workspace too small for interleaved grids)
__global__ __launch_bounds__(256) void feat_s_kernel(
    const float* __restrict__ x,
    const float* __restrict__ g0, const float* __restrict__ g1,
    const float* __restrict__ g2, const float* __restrict__ g3,
    const float* __restrict__ coef,
    unsigned short* __restrict__ feats) {
    int i = blockIdx.x * 256 + threadIdx.x;
    float px = x[3 * i + 0], py = x[3 * i + 1], pz = x[3 * i + 2];

    float4 cf = trilerp4s<64>(coef, px, py, pz);
    float4 t0 = trilerp4s<32>(g0, encf(px, 1.f), encf(py, 1.f), encf(pz, 1.f));
    float4 t1 = trilerp4s<64>(g1, encf(px, 2.f), encf(py, 2.f), encf(pz, 2.f));
    float4 t2 = trilerp4s<128>(g2, encf(px, 4.f), encf(py, 4.f), encf(pz, 4.f));
    float4 t3 = trilerp4s<256>(g3, encf(px, 8.f), encf(py, 8.f), encf(pz, 8.f));

    float o[16];
    o[0] = t0.x * cf.x; o[1] = t0.y * cf.x; o[2] = t0.z * cf.x; o[3] = t0.w * cf.x;
    o[4] = t1.x * cf.y; o[5] = t1.y * cf.y; o[6] = t1.z * cf.y; o[7] = t1.w * cf.y;
    o[8] = t2.x * cf.z; o[9] = t2.y * cf.z; o[10] = t2.z * cf.z; o[11] = t2.w * cf.z;
    o[12] = t3.x * cf.w; o[13] = t3.y * cf.w; o[14] = t3.z * cf.w; o[15] = t3.w * cf.w;

    bf16x8 lo, hi;
#pragma unroll
    for (int j = 0; j < 8; ++j) {
        lo[j] = (short)f2bf(o[j]);
        hi[j] = (short)f2bf(o[8 + j]);
    }
    bf16x8* dst = (bf16x8*)(feats + (size_t)i * 16);
    dst[0] = lo;
    dst[1] = hi;
}

// ---------------- kernel 2: weight prep -> MFMA-fragment order ----------------
// (unchanged — layout verified by bit-identical absmax)
__global__ __launch_bounds__(256) void prep_kernel(
    const float* __restrict__ W0, const float* __restrict__ W1,
    const float* __restrict__ W2, const float* __restrict__ W3,
    const float* __restrict__ W4, const float* __restrict__ W5,
    const float* __restrict__ W6,
    const float* __restrict__ B0, const float* __restrict__ B1,
    const float* __restrict__ B2, const float* __restrict__ B3,
    const float* __restrict__ B4, const float* __restrict__ B5,
    const float* __restrict__ B6,
    unsigned short* __restrict__ wt, float* __restrict__ biases) {
    int tid = blockIdx.x * 256 + threadIdx.x;
    if (tid < 102400) {
        int l, e;
        if (tid < 4096) { l = 0; e = tid; }
        else { l = 1 + (tid - 4096) / 16384; e = (tid - 4096) & 16383; }
        int j = e & 7;
        int lane = (e >> 3) & 63;
        int ni = (e >> 9) & 7;
        int kk = (e >> 12) & 3;
        int lr = lane & 15;
        int q = lane >> 4;
        int n = ni * 16 + lr;
        const float* W = (l == 0) ? W0 : (l == 1) ? W1 : (l == 2) ? W2
                        : (l == 3) ? W3 : (l == 4) ? W4 : (l == 5) ? W5 : W6;
        float v;
        if (l == 0) {
            int k = q * 8 + j;
            v = (k < 16) ? W[k * 128 + n] : 0.0f;
        } else {
            int h = (2 * kk + (j >> 2)) * 16 + q * 4 + (j & 3);
            v = W[h * 128 + n];
        }
        wt[tid] = f2bf(v);
    } else if (tid < 102400 + 896) {
        int e = tid - 102400;
        int l = e >> 7;
        const float* B = (l == 0) ? B0 : (l == 1) ? B1 : (l == 2) ? B2
                        : (l == 3) ? B3 : (l == 4) ? B4 : (l == 5) ? B5 : B6;
        biases[e] = B[e & 127];
    }
}

// ---------------- kernel 3: fused 7-layer MLP (512 threads, 8 waves) ----------
// Register-local pi-transition + double-buffered LDS weight staging. 8 waves x
// 64 rows = 512 rows/block: the 32KB/layer staging now serves 2x the rows and
// block count halves (fewer barrier convoys). Per-thread register footprint is
// unchanged from the 4-wave version.
#define WBUF 16640  // shorts per buffer (16384 weight shorts + 256 shorts of fp32 bias)

__device__ __forceinline__ void stage16(const unsigned short* __restrict__ gsrc,
                                        unsigned short* lbase) {
    __builtin_amdgcn_global_load_lds(
        (const __attribute__((address_space(1))) void*)gsrc,
        (__attribute__((address_space(3))) void*)lbase, 16, 0, 0);
}

__global__ __launch_bounds__(512, 2) void mlp_kernel(
    const unsigned short* __restrict__ feats,
    const int* __restrict__ invPos,
    const unsigned short* __restrict__ wt,
    const float* __restrict__ biases,
    float* __restrict__ out) {
    __shared__ __attribute__((aligned(16))) unsigned short Wlds[2 * WBUF];

    const int t = threadIdx.x;
    const int lane = t & 63;
    const int w = t >> 6;                     // 0..7
    const int lr = lane & 15;
    const int q = lane >> 4;
    const size_t rowq = (size_t)blockIdx.x * 512 + w * 64;  // wave's first row

    // ---- prologue: stage layer-0 weights (8KB) + bias0; load H0 frags ----
    {
        // 8 wave-chunks of 1KB: each of the 8 waves stages exactly one
        stage16(wt + w * 512 + lane * 8, Wlds + w * 512);
        if (t < 128) ((float*)(Wlds + 16384))[t] = biases[t];
    }

    bf16x8 h0[4];
#pragma unroll
    for (int mi = 0; mi < 4; ++mi) {
        size_t r = rowq + mi * 16 + lr;
        size_t p = invPos ? (size_t)invPos[r] : r;
        if (q < 2)
            h0[mi] = *(const bf16x8*)(feats + p * 16 + q * 8);
        else
            h0[mi] = (bf16x8)0;
    }
    __syncthreads();   // buf0 (L0) ready

    f32x4 acc[4][8];

    // ---- layer 0: K=16 (padded to 32) ----
    {
        const unsigned short* w1 = wt + 4096;
#pragma unroll
        for (int i = 0; i < 4; ++i) {
            int idx = i * 8 + w;                    // 0..31
            stage16(w1 + idx * 512 + lane * 8, Wlds + WBUF + idx * 512);
        }
        if (t < 128) ((float*)(Wlds + WBUF + 16384))[t] = biases[128 + t];

        const unsigned short* cw = Wlds;
        const float* cb = (const float*)(Wlds + 16384);
#pragma unroll
        for (int ni = 0; ni < 8; ++ni) {
            f32x4 bv = *(const f32x4*)(cb + ni * 16 + q * 4);
#pragma unroll
            for (int mi = 0; mi < 4; ++mi) acc[mi][ni] = bv;
        }
#pragma unroll
        for (int ni = 0; ni < 8; ++ni) {
            bf16x8 wf = *(const bf16x8*)(cw + (ni * 64 + lane) * 8);
#pragma unroll
            for (int mi = 0; mi < 4; ++mi)
                acc[mi][ni] = __builtin_amdgcn_mfma_f32_16x16x32_bf16(
                    wf, h0[mi], acc[mi][ni], 0, 0, 0);
        }
        __syncthreads();  // drains staging vmcnt -> buf1 ready; buf0 reads done
    }

    // ---- layers 1..6 ----
    bf16x8 hf[4][4];
    for (int l = 1; l < 7; ++l) {
        unsigned short* cwm = Wlds + (l & 1) * WBUF;
        if (l < 6) {
            const unsigned short* wn = wt + 4096 + l * 16384;
            unsigned short* nb = Wlds + ((l + 1) & 1) * WBUF;
#pragma unroll
            for (int i = 0; i < 4; ++i) {
                int idx = i * 8 + w;
                stage16(wn + idx * 512 + lane * 8, nb + idx * 512);
            }
            if (t < 128) ((float*)(nb + 16384))[t] = biases[(l + 1) * 128 + t];
        }

        // acc (bias included) -> relu -> bf16 B-frags, register-local (pi in wt)
#pragma unroll
        for (int mi = 0; mi < 4; ++mi)
#pragma unroll
            for (int kk = 0; kk < 4; ++kk) {
                bf16x8 v;
#pragma unroll
                for (int jp = 0; jp < 8; ++jp)
                    v[jp] = (short)f2bf(fmaxf(acc[mi][2 * kk + (jp >> 2)][jp & 3], 0.0f));
                hf[mi][kk] = v;
            }
        const float* cb = (const float*)(cwm + 16384);
#pragma unroll
        for (int ni = 0; ni < 8; ++ni) {
            f32x4 bv = *(const f32x4*)(cb + ni * 16 + q * 4);
#pragma unroll
            for (int mi = 0; mi < 4; ++mi) acc[mi][ni] = bv;
        }
#pragma unroll
        for (int kk = 0; kk < 4; ++kk) {
            bf16x8 wf[8];
#pragma unroll
            for (int ni = 0; ni < 8; ++ni)
                wf[ni] = *(const bf16x8*)(cwm + ((kk * 8 + ni) * 64 + lane) * 8);
#pragma unroll
            for (int ni = 0; ni < 8; ++ni)
#pragma unroll
                for (int mi = 0; mi < 4; ++mi)
                    acc[mi][ni] = __builtin_amdgcn_mfma_f32_16x16x32_bf16(
                        wf[ni], hf[mi][kk], acc[mi][ni], 0, 0, 0);
        }
        if (l < 6) __syncthreads();
    }

    // ---- epilogue: layer 6 has no relu; bias already in acc ----
#pragma unroll
    for (int mi = 0; mi < 4; ++mi)
#pragma unroll
        for (int ni = 0; ni < 8; ++ni) {
            *(f32x4*)(&out[(rowq + mi * 16 + lr) * 128 + ni * 16 + q * 4]) =
                acc[mi][ni];
        }
}

extern "C" void kernel_launch(void* const* d_in, const int* in_sizes, int n_in,
                              void* d_out, int out_size, void* d_ws, size_t ws_size,
                              hipStream_t stream) {
    const float* x = (const float*)d_in[0];
    const float* g0 = (const float*)d_in[1];
    const float* g1 = (const float*)d_in[2];
    const float* g2 = (const float*)d_in[3];
    const float* g3 = (const float*)d_in[4];
    const float* coef = (const float*)d_in[5];
    const float* W[7];
    const float* B[7];
    for (int j = 0; j < 7; ++j) {
        W[j] = (const float*)d_in[6 + 2 * j];
        B[j] = (const float*)d_in[7 + 2 * j];
    }

    // workspace layout (bytes), fp16 interleaved grids + atomic-free sort:
    //   feats      @ 0          16,777,216   (bf16 [N][16], SORTED order on fast2)
    //   wt         @ 16777216      204,800   (bf16 fragment-order weights)
    //   biases     @ 16982016        3,584   (fp32 [7][128])
    //   coefi      @ 16985600    2,097,152   (fp16 [64^3][4])
    //   g0i        @ 19082752      262,144
    //   g1i        @ 19344896    2,097,152
    //   g2i        @ 21442048   16,777,216   -> 38,219,264
    //   hist2d     @ 38219264    2,097,152   (u32 [512][1024])
    //   start2d    @ 40316416    2,097,152   (u32 [512][1024])
    //   totals     @ 42413568        4,096
    //   bucketBase @ 42417664        4,096
    //   rec        @ 42421760    8,388,608   (float4 sorted points)
    //   invPos     @ 50810368    2,097,152   -> end 52,907,520
    // g3i (fp16 [256^3][4] = 134,217,728 B) aliases d_out (out is 268 MB),
    // safe: ileave -> feat(read) -> mlp(write) are stream-ordered.
    char* ws = (char*)d_ws;
    unsigned short* feats = (unsigned short*)ws;
    unsigned short* wt = (unsigned short*)(ws + 16777216);
    float* biases = (float*)(ws + 16982016);
    unsigned short* coefi = (unsigned short*)(ws + 16985600);
    unsigned short* g0i = (unsigned short*)(ws + 19082752);
    unsigned short* g1i = (unsigned short*)(ws + 19344896);
    unsigned short* g2i = (unsigned short*)(ws + 21442048);
    unsigned* hist2d = (unsigned*)(ws + 38219264);
    unsigned* start2d = (unsigned*)(ws + 40316416);
    unsigned* totals = (unsigned*)(ws + 42413568);
    unsigned* bucketBase = (unsigned*)(ws + 42417664);
    float4* rec = (float4*)(ws + 42421760);
    int* invPos = (int*)(ws + 50810368);
    unsigned short* g3i = (unsigned short*)d_out;

    prep_kernel<<<404, 256, 0, stream>>>(W[0], W[1], W[2], W[3], W[4], W[5], W[6],
                                         B[0], B[1], B[2], B[3], B[4], B[5], B[6],
                                         wt, biases);

    bool fast = ws_size >= 38219264ull;
    bool fast2 = ws_size >= 52907520ull;
    if (fast) {
        ileaveh_kernel<64><<<1024, 256, 0, stream>>>(coef, coefi);
        ileaveh_kernel<32><<<128, 256, 0, stream>>>(g0, g0i);
        ileaveh_kernel<64><<<1024, 256, 0, stream>>>(g1, g1i);
        ileaveh_kernel<128><<<8192, 256, 0, stream>>>(g2, g2i);
        ileaveh_kernel<256><<<65536, 256, 0, stream>>>(g3, g3i);
        if (fast2) {
            hist2_kernel<<<NSBLK, 256, 0, stream>>>(x, hist2d);
            scanb_kernel<<<NBUCK, 64, 0, stream>>>(hist2d, start2d, totals);
            scan_kernel<<<1, 1024, 0, stream>>>(totals, bucketBase);
            scatter2_kernel<<<NSBLK, 256, 0, stream>>>(x, start2d, bucketBase,
                                                       rec, invPos);
            feat_sorted_kernel<<<N_PTS / 512, 256, 0, stream>>>(rec, g0i, g1i, g2i,
                                                                g3i, coefi, feats);
            mlp_kernel<<<N_PTS / 512, 512, 0, stream>>>(feats, invPos, wt, biases,
                                                        (float*)d_out);
        } else {
            feat_i_kernel<<<N_PTS / 256, 256, 0, stream>>>(x, g0i, g1i, g2i, g3i,
                                                           coefi, feats);
            mlp_kernel<<<N_PTS / 512, 512, 0, stream>>>(feats, nullptr, wt, biases,
                                                        (float*)d_out);
        }
    } else {
        feat_s_kernel<<<N_PTS / 256, 256, 0, stream>>>(x, g0, g1, g2, g3, coef,
                                                       feats);
        mlp_kernel<<<N_PTS / 512, 512, 0, stream>>>(feats, nullptr, wt, biases,
                                                    (float*)d_out);
    }
}

// Round 8
// 725.617 us; speedup vs baseline: 1.0597x; 1.0597x over previous
//
#include <hip/hip_runtime.h>
#include <hip/hip_fp16.h>

#define N_PTS 524288
#define NBUCK 1024
#define SBLK 1024               // points per sort block
#define NSBLK (N_PTS / SBLK)    // 512

typedef __attribute__((ext_vector_type(8))) short bf16x8;
typedef __attribute__((ext_vector_type(4))) short bf16x4;
typedef __attribute__((ext_vector_type(4))) float f32x4;
typedef __attribute__((ext_vector_type(4))) unsigned int u32x4;

// float -> bf16 (round-to-nearest-even), bit pattern in ushort
__device__ __forceinline__ unsigned short f2bf(float f) {
    unsigned u = __builtin_bit_cast(unsigned, f);
    u = (u + 0x7FFFu + ((u >> 16) & 1u)) >> 16;
    return (unsigned short)u;
}

// packed RNE f32x2 -> bf16x2 (low=a, high=b) — native gfx950 instr; same RNE
// rounding as f2bf but 1 VALU op instead of ~8.
__device__ __forceinline__ unsigned cvtpk_bf16(float a, float b) {
    unsigned r;
    asm("v_cvt_pk_bf16_f32 %0, %1, %2" : "=v"(r) : "v"(a), "v"(b));
    return r;
}

__device__ __forceinline__ float encf(float v, float f) {
    float t = v * f;
    return 2.0f * (t - floorf(t)) - 1.0f;   // jnp: 2*(f*x % 1) - 1
}

// spatial bucket key: top bits of the g3 (256^3, freq-8) integer coords.
// 10 bits: (iz>>4)<<6 | (iy>>5)<<3 | (ix>>5). Must be identical in hist/scatter.
__device__ __forceinline__ int bucket_of(float px, float py, float pz) {
    float cx = (encf(px, 8.f) + 1.0f) * 127.5f;
    float cy = (encf(py, 8.f) + 1.0f) * 127.5f;
    float cz = (encf(pz, 8.f) + 1.0f) * 127.5f;
    int ix = min(max((int)floorf(cx), 0), 255);
    int iy = min(max((int)floorf(cy), 0), 255);
    int iz = min(max((int)floorf(cz), 0), 255);
    return ((iz >> 4) << 6) | ((iy >> 5) << 3) | (ix >> 5);
}

// ---------------- sort pass kernels (ZERO global atomics) ----------------
// pass 1: per-block LDS histogram -> hist2d[blk][NBUCK] (coalesced)
__global__ __launch_bounds__(256) void hist2_kernel(const float* __restrict__ x,
                                                    unsigned* __restrict__ hist2d) {
    __shared__ unsigned lh[NBUCK];
    int t = threadIdx.x;
    int blk = blockIdx.x;
#pragma unroll
    for (int i = 0; i < 4; ++i) lh[t + i * 256] = 0u;
    __syncthreads();
#pragma unroll
    for (int i = 0; i < 4; ++i) {
        int gid = blk * SBLK + i * 256 + t;
        atomicAdd(&lh[bucket_of(x[3 * gid], x[3 * gid + 1], x[3 * gid + 2])], 1u);
    }
    __syncthreads();
#pragma unroll
    for (int i = 0; i < 4; ++i)
        hist2d[(size_t)blk * NBUCK + t + i * 256] = lh[t + i * 256];
}

// pass 2: per-bucket scan over the 512 block counts (1 wave per bucket).
// start2d[blk][j] = # of bucket-j points in blocks < blk; totals[j] = count.
__global__ __launch_bounds__(64) void scanb_kernel(const unsigned* __restrict__ hist2d,
                                                   unsigned* __restrict__ start2d,
                                                   unsigned* __restrict__ totals) {
    int j = blockIdx.x;         // bucket
    int lane = threadIdx.x;     // 0..63, covers blocks [lane*8, lane*8+8)
    int b0 = lane * 8;
    unsigned c[8];
#pragma unroll
    for (int k = 0; k < 8; ++k) c[k] = hist2d[(size_t)(b0 + k) * NBUCK + j];
    unsigned s = 0;
#pragma unroll
    for (int k = 0; k < 8; ++k) s += c[k];
    // wave-exclusive scan of s across 64 lanes
    unsigned v = s;
    for (int off = 1; off < 64; off <<= 1) {
        unsigned u = __shfl_up(v, off, 64);
        if (lane >= off) v += u;
    }
    unsigned run = v - s;       // exclusive prefix
#pragma unroll
    for (int k = 0; k < 8; ++k) {
        start2d[(size_t)(b0 + k) * NBUCK + j] = run;
        run += c[k];
    }
    if (lane == 63) totals[j] = run;
}

// pass 3: exclusive scan of bucket totals -> bucketBase
__global__ __launch_bounds__(1024) void scan_kernel(const unsigned* __restrict__ totals,
                                                    unsigned* __restrict__ bucketBase) {
    __shared__ unsigned s[NBUCK];
    int t = threadIdx.x;
    unsigned mine = totals[t];
    s[t] = mine;
    __syncthreads();
    for (int off = 1; off < NBUCK; off <<= 1) {
        unsigned v = (t >= off) ? s[t - off] : 0u;
        __syncthreads();
        s[t] += v;
        __syncthreads();
    }
    bucketBase[t] = s[t] - mine;   // exclusive prefix
}

// pass 4: deterministic scatter; local rank via LDS atomics only.
__global__ __launch_bounds__(256) void scatter2_kernel(
    const float* __restrict__ x,
    const unsigned* __restrict__ start2d,
    const unsigned* __restrict__ bucketBase,
    float4* __restrict__ rec, int* __restrict__ invPos) {
    __shared__ unsigned lc[NBUCK];
    int t = threadIdx.x;
    int blk = blockIdx.x;
#pragma unroll
    for (int i = 0; i < 4; ++i) lc[t + i * 256] = 0u;
    __syncthreads();
#pragma unroll
    for (int i = 0; i < 4; ++i) {
        int gid = blk * SBLK + i * 256 + t;
        float px = x[3 * gid], py = x[3 * gid + 1], pz = x[3 * gid + 2];
        int b = bucket_of(px, py, pz);
        unsigned lrank = atomicAdd(&lc[b], 1u);   // LDS atomic: cheap
        unsigned pos = bucketBase[b] + start2d[(size_t)blk * NBUCK + b] + lrank;
        rec[pos] = make_float4(px, py, pz, 0.0f);
        invPos[gid] = (int)pos;
    }
}

// ---------------- channel-interleave to fp16: [4][R^3] -> [R^3][4] ----------------
template <int R>
__global__ __launch_bounds__(256) void ileaveh_kernel(const float* __restrict__ g,
                                                      unsigned short* __restrict__ gi) {
    constexpr int V = R * R * R;
    int idx = blockIdx.x * 256 + threadIdx.x;
    ushort4 v;
    v.x = __half_as_ushort(__float2half(g[idx]));
    v.y = __half_as_ushort(__float2half(g[idx + V]));
    v.z = __half_as_ushort(__float2half(g[idx + 2 * V]));
    v.w = __half_as_ushort(__float2half(g[idx + 3 * V]));
    *(ushort4*)(&gi[(size_t)idx * 4]) = v;
}

__device__ __forceinline__ float4 h4f(const unsigned short* p) {
    uint2 u = *(const uint2*)p;
    float4 r;
    r.x = __half2float(__ushort_as_half((unsigned short)(u.x & 0xffffu)));
    r.y = __half2float(__ushort_as_half((unsigned short)(u.x >> 16)));
    r.z = __half2float(__ushort_as_half((unsigned short)(u.y & 0xffffu)));
    r.w = __half2float(__ushort_as_half((unsigned short)(u.y >> 16)));
    return r;
}

// trilerp over fp16 channel-interleaved grid: one 8B load per corner
template <int R>
__device__ __forceinline__ float4 trilerp4h(const unsigned short* __restrict__ gi,
                                            float px, float py, float pz) {
    constexpr float S = 0.5f * (float)(R - 1);
    float cx = (px + 1.0f) * S;
    float cy = (py + 1.0f) * S;
    float cz = (pz + 1.0f) * S;
    float fx0 = floorf(cx), fy0 = floorf(cy), fz0 = floorf(cz);
    float fx = cx - fx0, fy = cy - fy0, fz = cz - fz0;
    int ix0 = min(max((int)fx0, 0), R - 1);
    int iy0 = min(max((int)fy0, 0), R - 1);
    int iz0 = min(max((int)fz0, 0), R - 1);
    int dx = (ix0 < R - 1) ? 4 : 0;           // offsets in ushorts (4 ch)
    int dy = (iy0 < R - 1) ? 4 * R : 0;
    int dz = (iz0 < R - 1) ? 4 * R * R : 0;
    const unsigned short* p = gi + 4 * ((size_t)iz0 * (R * R) + iy0 * R + ix0);

    float4 v000 = h4f(p);
    float4 v001 = h4f(p + dx);
    float4 v010 = h4f(p + dy);
    float4 v011 = h4f(p + dy + dx);
    float4 v100 = h4f(p + dz);
    float4 v101 = h4f(p + dz + dx);
    float4 v110 = h4f(p + dz + dy);
    float4 v111 = h4f(p + dz + dy + dx);

    float gx0 = 1.0f - fx, gy0 = 1.0f - fy, gz0 = 1.0f - fz;
    float w00 = gz0 * gy0, w01 = gz0 * fy, w10 = fz * gy0, w11 = fz * fy;
    float w000 = w00 * gx0, w001 = w00 * fx;
    float w010 = w01 * gx0, w011 = w01 * fx;
    float w100 = w10 * gx0, w101 = w10 * fx;
    float w110 = w11 * gx0, w111 = w11 * fx;

    float4 r;
    r.x = v000.x * w000 + v001.x * w001 + v010.x * w010 + v011.x * w011 +
          v100.x * w100 + v101.x * w101 + v110.x * w110 + v111.x * w111;
    r.y = v000.y * w000 + v001.y * w001 + v010.y * w010 + v011.y * w011 +
          v100.y * w100 + v101.y * w101 + v110.y * w110 + v111.y * w111;
    r.z = v000.z * w000 + v001.z * w001 + v010.z * w010 + v011.z * w011 +
          v100.z * w100 + v101.z * w101 + v110.z * w110 + v111.z * w111;
    r.w = v000.w * w000 + v001.w * w001 + v010.w * w010 + v011.w * w011 +
          v100.w * w100 + v101.w * w101 + v110.w * w110 + v111.w * w111;
    return r;
}

// strided (original-layout fp32) trilerp — fallback path only
template <int R>
__device__ __forceinline__ float4 trilerp4s(const float* __restrict__ g,
                                            float px, float py, float pz) {
    constexpr float S = 0.5f * (float)(R - 1);
    float cx = (px + 1.0f) * S;
    float cy = (py + 1.0f) * S;
    float cz = (pz + 1.0f) * S;
    float fx0 = floorf(cx), fy0 = floorf(cy), fz0 = floorf(cz);
    float fx = cx - fx0, fy = cy - fy0, fz = cz - fz0;
    int ix0 = min(max((int)fx0, 0), R - 1);
    int iy0 = min(max((int)fy0, 0), R - 1);
    int iz0 = min(max((int)fz0, 0), R - 1);
    int dx = (ix0 < R - 1) ? 1 : 0;
    int dy = (iy0 < R - 1) ? R : 0;
    int dz = (iz0 < R - 1) ? R * R : 0;
    int base = iz0 * (R * R) + iy0 * R + ix0;

    float gx0 = 1.0f - fx, gy0 = 1.0f - fy, gz0 = 1.0f - fz;
    float w00 = gz0 * gy0, w01 = gz0 * fy, w10 = fz * gy0, w11 = fz * fy;
    float w000 = w00 * gx0, w001 = w00 * fx;
    float w010 = w01 * gx0, w011 = w01 * fx;
    float w100 = w10 * gx0, w101 = w10 * fx;
    float w110 = w11 * gx0, w111 = w11 * fx;

    float4 out;
    float r[4];
#pragma unroll
    for (int c = 0; c < 4; ++c) {
        const float* gc = g + (size_t)c * (R * R * R);
        r[c] = gc[base] * w000 + gc[base + dx] * w001 + gc[base + dy] * w010 +
               gc[base + dy + dx] * w011 + gc[base + dz] * w100 +
               gc[base + dz + dx] * w101 + gc[base + dz + dy] * w110 +
               gc[base + dz + dy + dx] * w111;
    }
    out.x = r[0]; out.y = r[1]; out.z = r[2]; out.w = r[3];
    return out;
}

// shared feature math: grids -> 16 bf16 feature shorts at feats[i*16]
__device__ __forceinline__ void feat_core(
    float px, float py, float pz,
    const unsigned short* __restrict__ g0i, const unsigned short* __restrict__ g1i,
    const unsigned short* __restrict__ g2i, const unsigned short* __restrict__ g3i,
    const unsigned short* __restrict__ coefi,
    unsigned short* __restrict__ feats, size_t i) {
    float4 cf = trilerp4h<64>(coefi, px, py, pz);
    float4 t0 = trilerp4h<32>(g0i, encf(px, 1.f), encf(py, 1.f), encf(pz, 1.f));
    float4 t1 = trilerp4h<64>(g1i, encf(px, 2.f), encf(py, 2.f), encf(pz, 2.f));
    float4 t2 = trilerp4h<128>(g2i, encf(px, 4.f), encf(py, 4.f), encf(pz, 4.f));
    float4 t3 = trilerp4h<256>(g3i, encf(px, 8.f), encf(py, 8.f), encf(pz, 8.f));

    float o[16];
    o[0] = t0.x * cf.x; o[1] = t0.y * cf.x; o[2] = t0.z * cf.x; o[3] = t0.w * cf.x;
    o[4] = t1.x * cf.y; o[5] = t1.y * cf.y; o[6] = t1.z * cf.y; o[7] = t1.w * cf.y;
    o[8] = t2.x * cf.z; o[9] = t2.y * cf.z; o[10] = t2.z * cf.z; o[11] = t2.w * cf.z;
    o[12] = t3.x * cf.w; o[13] = t3.y * cf.w; o[14] = t3.z * cf.w; o[15] = t3.w * cf.w;

    bf16x8 lo, hi;
#pragma unroll
    for (int j = 0; j < 8; ++j) {
        lo[j] = (short)f2bf(o[j]);
        hi[j] = (short)f2bf(o[8 + j]);
    }
    bf16x8* dst = (bf16x8*)(feats + i * 16);
    dst[0] = lo;
    dst[1] = hi;
}

// ---------------- kernel 1a: features from SORTED records (1 pt/thread) --------
__global__ __launch_bounds__(256) void feat_sorted_kernel(
    const float4* __restrict__ rec,
    const unsigned short* __restrict__ g0i, const unsigned short* __restrict__ g1i,
    const unsigned short* __restrict__ g2i, const unsigned short* __restrict__ g3i,
    const unsigned short* __restrict__ coefi,
    unsigned short* __restrict__ feats) {
    int i = blockIdx.x * 256 + threadIdx.x;
    float4 r = rec[i];
    feat_core(r.x, r.y, r.z, g0i, g1i, g2i, g3i, coefi, feats, (size_t)i);
}

// ---------------- kernel 1b: features in original order (no sort) ----------------
__global__ __launch_bounds__(256) void feat_i_kernel(
    const float* __restrict__ x,
    const unsigned short* __restrict__ g0i, const unsigned short* __restrict__ g1i,
    const unsigned short* __restrict__ g2i, const unsigned short* __restrict__ g3i,
    const unsigned short* __restrict__ coefi,
    unsigned short* __restrict__ feats) {
    int i = blockIdx.x * 256 + threadIdx.x;
    feat_core(x[3 * i], x[3 * i + 1], x[3 * i + 2], g0i, g1i, g2i, g3i, coefi,
              feats, (size_t)i);
}

// fallback (workspace too small for interleaved grids)
__global__ __launch_bounds__(256) void feat_s_kernel(
    const float* __restrict__ x,
    const float* __restrict__ g0, const float* __restrict__ g1,
    const float* __restrict__ g2, const float* __restrict__ g3,
    const float* __restrict__ coef,
    unsigned short* __restrict__ feats) {
    int i = blockIdx.x * 256 + threadIdx.x;
    float px = x[3 * i + 0], py = x[3 * i + 1], pz = x[3 * i + 2];

    float4 cf = trilerp4s<64>(coef, px, py, pz);
    float4 t0 = trilerp4s<32>(g0, encf(px, 1.f), encf(py, 1.f), encf(pz, 1.f));
    float4 t1 = trilerp4s<64>(g1, encf(px, 2.f), encf(py, 2.f), encf(pz, 2.f));
    float4 t2 = trilerp4s<128>(g2, encf(px, 4.f), encf(py, 4.f), encf(pz, 4.f));
    float4 t3 = trilerp4s<256>(g3, encf(px, 8.f), encf(py, 8.f), encf(pz, 8.f));

    float o[16];
    o[0] = t0.x * cf.x; o[1] = t0.y * cf.x; o[2] = t0.z * cf.x; o[3] = t0.w * cf.x;
    o[4] = t1.x * cf.y; o[5] = t1.y * cf.y; o[6] = t1.z * cf.y; o[7] = t1.w * cf.y;
    o[8] = t2.x * cf.z; o[9] = t2.y * cf.z; o[10] = t2.z * cf.z; o[11] = t2.w * cf.z;
    o[12] = t3.x * cf.w; o[13] = t3.y * cf.w; o[14] = t3.z * cf.w; o[15] = t3.w * cf.w;

    bf16x8 lo, hi;
#pragma unroll
    for (int j = 0; j < 8; ++j) {
        lo[j] = (short)f2bf(o[j]);
        hi[j] = (short)f2bf(o[8 + j]);
    }
    bf16x8* dst = (bf16x8*)(feats + (size_t)i * 16);
    dst[0] = lo;
    dst[1] = hi;
}

// ---------------- kernel 2: weight prep -> MFMA-fragment order ----------------
// (unchanged — layout verified by bit-identical absmax)
__global__ __launch_bounds__(256) void prep_kernel(
    const float* __restrict__ W0, const float* __restrict__ W1,
    const float* __restrict__ W2, const float* __restrict__ W3,
    const float* __restrict__ W4, const float* __restrict__ W5,
    const float* __restrict__ W6,
    const float* __restrict__ B0, const float* __restrict__ B1,
    const float* __restrict__ B2, const float* __restrict__ B3,
    const float* __restrict__ B4, const float* __restrict__ B5,
    const float* __restrict__ B6,
    unsigned short* __restrict__ wt, float* __restrict__ biases) {
    int tid = blockIdx.x * 256 + threadIdx.x;
    if (tid < 102400) {
        int l, e;
        if (tid < 4096) { l = 0; e = tid; }
        else { l = 1 + (tid - 4096) / 16384; e = (tid - 4096) & 16383; }
        int j = e & 7;
        int lane = (e >> 3) & 63;
        int ni = (e >> 9) & 7;
        int kk = (e >> 12) & 3;
        int lr = lane & 15;
        int q = lane >> 4;
        int n = ni * 16 + lr;
        const float* W = (l == 0) ? W0 : (l == 1) ? W1 : (l == 2) ? W2
                        : (l == 3) ? W3 : (l == 4) ? W4 : (l == 5) ? W5 : W6;
        float v;
        if (l == 0) {
            int k = q * 8 + j;
            v = (k < 16) ? W[k * 128 + n] : 0.0f;
        } else {
            int h = (2 * kk + (j >> 2)) * 16 + q * 4 + (j & 3);
            v = W[h * 128 + n];
        }
        wt[tid] = f2bf(v);
    } else if (tid < 102400 + 896) {
        int e = tid - 102400;
        int l = e >> 7;
        const float* B = (l == 0) ? B0 : (l == 1) ? B1 : (l == 2) ? B2
                        : (l == 3) ? B3 : (l == 4) ? B4 : (l == 5) ? B5 : B6;
        biases[e] = B[e & 127];
    }
}

// ---------------- kernel 3: fused 7-layer MLP (round-6 structure) ----------
// 4 waves x 64 rows; register-local pi-transition; double-buffered LDS weight
// staging. Round-8 change: repack uses v_cvt_pk_bf16_f32 (16 packed converts
// replace 128 bit-op f2bf) — round-7 counters showed VALUBusy 38.5% >
// MfmaUtil 27.7%, i.e. the repack VALU chain is on the critical path.
#define WBUF 16640  // shorts per buffer (16384 weight shorts + 256 shorts of fp32 bias)

__device__ __forceinline__ void stage16(const unsigned short* __restrict__ gsrc,
                                        unsigned short* lbase) {
    __builtin_amdgcn_global_load_lds(
        (const __attribute__((address_space(1))) void*)gsrc,
        (__attribute__((address_space(3))) void*)lbase, 16, 0, 0);
}

__global__ __launch_bounds__(256, 2) void mlp_kernel(
    const unsigned short* __restrict__ feats,
    const int* __restrict__ invPos,
    const unsigned short* __restrict__ wt,
    const float* __restrict__ biases,
    float* __restrict__ out) {
    __shared__ __attribute__((aligned(16))) unsigned short Wlds[2 * WBUF];

    const int t = threadIdx.x;
    const int lane = t & 63;
    const int w = t >> 6;
    const int lr = lane & 15;
    const int q = lane >> 4;
    const size_t rowq = (size_t)blockIdx.x * 256 + w * 64;  // wave's first row

    // ---- prologue: stage layer-0 weights (8KB) + bias0; load H0 frags ----
    {
#pragma unroll
        for (int i = 0; i < 2; ++i) {
            int idx = i * 4 + w;                    // wave-chunk 0..7
            stage16(wt + idx * 512 + lane * 8, Wlds + idx * 512);
        }
        if (t < 128) ((float*)(Wlds + 16384))[t] = biases[t];
    }

    bf16x8 h0[4];
#pragma unroll
    for (int mi = 0; mi < 4; ++mi) {
        size_t r = rowq + mi * 16 + lr;
        size_t p = invPos ? (size_t)invPos[r] : r;
        if (q < 2)
            h0[mi] = *(const bf16x8*)(feats + p * 16 + q * 8);
        else
            h0[mi] = (bf16x8)0;
    }
    __syncthreads();   // buf0 (L0) ready

    f32x4 acc[4][8];

    // ---- layer 0: K=16 (padded to 32) ----
    {
        const unsigned short* w1 = wt + 4096;
#pragma unroll
        for (int i = 0; i < 8; ++i) {
            int idx = i * 4 + w;                    // 0..31
            stage16(w1 + idx * 512 + lane * 8, Wlds + WBUF + idx * 512);
        }
        if (t < 128) ((float*)(Wlds + WBUF + 16384))[t] = biases[128 + t];

        const unsigned short* cw = Wlds;
        const float* cb = (const float*)(Wlds + 16384);
#pragma unroll
        for (int ni = 0; ni < 8; ++ni) {
            f32x4 bv = *(const f32x4*)(cb + ni * 16 + q * 4);
#pragma unroll
            for (int mi = 0; mi < 4; ++mi) acc[mi][ni] = bv;
        }
#pragma unroll
        for (int ni = 0; ni < 8; ++ni) {
            bf16x8 wf = *(const bf16x8*)(cw + (ni * 64 + lane) * 8);
#pragma unroll
            for (int mi = 0; mi < 4; ++mi)
                acc[mi][ni] = __builtin_amdgcn_mfma_f32_16x16x32_bf16(
                    wf, h0[mi], acc[mi][ni], 0, 0, 0);
        }
        __syncthreads();  // drains staging vmcnt -> buf1 ready; buf0 reads done
    }

    // ---- layers 1..6 ----
    bf16x8 hf[4][4];
    for (int l = 1; l < 7; ++l) {
        unsigned short* cwm = Wlds + (l & 1) * WBUF;
        if (l < 6) {
            const unsigned short* wn = wt + 4096 + l * 16384;
            unsigned short* nb = Wlds + ((l + 1) & 1) * WBUF;
#pragma unroll
            for (int i = 0; i < 8; ++i) {
                int idx = i * 4 + w;
                stage16(wn + idx * 512 + lane * 8, nb + idx * 512);
            }
            if (t < 128) ((float*)(nb + 16384))[t] = biases[(l + 1) * 128 + t];
        }

        // acc (bias included) -> relu -> bf16 B-frags, register-local (pi in wt).
        // Word w2 of hf[mi][kk] holds elements jp=2*w2 (low) and 2*w2+1 (high):
        //   jp>>2 == w2>>1, jp&3 == (w2&1)*2 (+1 for high) — packed convert.
#pragma unroll
        for (int mi = 0; mi < 4; ++mi)
#pragma unroll
            for (int kk = 0; kk < 4; ++kk) {
                u32x4 wv;
#pragma unroll
                for (int w2 = 0; w2 < 4; ++w2) {
                    float a = fmaxf(acc[mi][2 * kk + (w2 >> 1)][(w2 & 1) * 2], 0.0f);
                    float b = fmaxf(acc[mi][2 * kk + (w2 >> 1)][(w2 & 1) * 2 + 1], 0.0f);
                    wv[w2] = cvtpk_bf16(a, b);
                }
                hf[mi][kk] = __builtin_bit_cast(bf16x8, wv);
            }
        const float* cb = (const float*)(cwm + 16384);
#pragma unroll
        for (int ni = 0; ni < 8; ++ni) {
            f32x4 bv = *(const f32x4*)(cb + ni * 16 + q * 4);
#pragma unroll
            for (int mi = 0; mi < 4; ++mi) acc[mi][ni] = bv;
        }
#pragma unroll
        for (int kk = 0; kk < 4; ++kk) {
            bf16x8 wf[8];
#pragma unroll
            for (int ni = 0; ni < 8; ++ni)
                wf[ni] = *(const bf16x8*)(cwm + ((kk * 8 + ni) * 64 + lane) * 8);
#pragma unroll
            for (int ni = 0; ni < 8; ++ni)
#pragma unroll
                for (int mi = 0; mi < 4; ++mi)
                    acc[mi][ni] = __builtin_amdgcn_mfma_f32_16x16x32_bf16(
                        wf[ni], hf[mi][kk], acc[mi][ni], 0, 0, 0);
        }
        if (l < 6) __syncthreads();
    }

    // ---- epilogue: layer 6 has no relu; bias already in acc ----
#pragma unroll
    for (int mi = 0; mi < 4; ++mi)
#pragma unroll
        for (int ni = 0; ni < 8; ++ni) {
            *(f32x4*)(&out[(rowq + mi * 16 + lr) * 128 + ni * 16 + q * 4]) =
                acc[mi][ni];
        }
}

extern "C" void kernel_launch(void* const* d_in, const int* in_sizes, int n_in,
                              void* d_out, int out_size, void* d_ws, size_t ws_size,
                              hipStream_t stream) {
    const float* x = (const float*)d_in[0];
    const float* g0 = (const float*)d_in[1];
    const float* g1 = (const float*)d_in[2];
    const float* g2 = (const float*)d_in[3];
    const float* g3 = (const float*)d_in[4];
    const float* coef = (const float*)d_in[5];
    const float* W[7];
    const float* B[7];
    for (int j = 0; j < 7; ++j) {
        W[j] = (const float*)d_in[6 + 2 * j];
        B[j] = (const float*)d_in[7 + 2 * j];
    }

    // workspace layout (bytes), fp16 interleaved grids + atomic-free sort:
    //   feats      @ 0          16,777,216   (bf16 [N][16], SORTED order on fast2)
    //   wt         @ 16777216      204,800   (bf16 fragment-order weights)
    //   biases     @ 16982016        3,584   (fp32 [7][128])
    //   coefi      @ 16985600    2,097,152   (fp16 [64^3][4])
    //   g0i        @ 19082752      262,144
    //   g1i        @ 19344896    2,097,152
    //   g2i        @ 21442048   16,777,216   -> 38,219,264
    //   hist2d     @ 38219264    2,097,152   (u32 [512][1024])
    //   start2d    @ 40316416    2,097,152   (u32 [512][1024])
    //   totals     @ 42413568        4,096
    //   bucketBase @ 42417664        4,096
    //   rec        @ 42421760    8,388,608   (float4 sorted points)
    //   invPos     @ 50810368    2,097,152   -> end 52,907,520
    // g3i (fp16 [256^3][4] = 134,217,728 B) aliases d_out (out is 268 MB),
    // safe: ileave -> feat(read) -> mlp(write) are stream-ordered.
    char* ws = (char*)d_ws;
    unsigned short* feats = (unsigned short*)ws;
    unsigned short* wt = (unsigned short*)(ws + 16777216);
    float* biases = (float*)(ws + 16982016);
    unsigned short* coefi = (unsigned short*)(ws + 16985600);
    unsigned short* g0i = (unsigned short*)(ws + 19082752);
    unsigned short* g1i = (unsigned short*)(ws + 19344896);
    unsigned short* g2i = (unsigned short*)(ws + 21442048);
    unsigned* hist2d = (unsigned*)(ws + 38219264);
    unsigned* start2d = (unsigned*)(ws + 40316416);
    unsigned* totals = (unsigned*)(ws + 42413568);
    unsigned* bucketBase = (unsigned*)(ws + 42417664);
    float4* rec = (float4*)(ws + 42421760);
    int* invPos = (int*)(ws + 50810368);
    unsigned short* g3i = (unsigned short*)d_out;

    prep_kernel<<<404, 256, 0, stream>>>(W[0], W[1], W[2], W[3], W[4], W[5], W[6],
                                         B[0], B[1], B[2], B[3], B[4], B[5], B[6],
                                         wt, biases);

    bool fast = ws_size >= 38219264ull;
    bool fast2 = ws_size >= 52907520ull;
    if (fast) {
        ileaveh_kernel<64><<<1024, 256, 0, stream>>>(coef, coefi);
        ileaveh_kernel<32><<<128, 256, 0, stream>>>(g0, g0i);
        ileaveh_kernel<64><<<1024, 256, 0, stream>>>(g1, g1i);
        ileaveh_kernel<128><<<8192, 256, 0, stream>>>(g2, g2i);
        ileaveh_kernel<256><<<65536, 256, 0, stream>>>(g3, g3i);
        if (fast2) {
            hist2_kernel<<<NSBLK, 256, 0, stream>>>(x, hist2d);
            scanb_kernel<<<NBUCK, 64, 0, stream>>>(hist2d, start2d, totals);
            scan_kernel<<<1, 1024, 0, stream>>>(totals, bucketBase);
            scatter2_kernel<<<NSBLK, 256, 0, stream>>>(x, start2d, bucketBase,
                                                       rec, invPos);
            feat_sorted_kernel<<<N_PTS / 256, 256, 0, stream>>>(rec, g0i, g1i, g2i,
                                                                g3i, coefi, feats);
            mlp_kernel<<<N_PTS / 256, 256, 0, stream>>>(feats, invPos, wt, biases,
                                                        (float*)d_out);
        } else {
            feat_i_kernel<<<N_PTS / 256, 256, 0, stream>>>(x, g0i, g1i, g2i, g3i,
                                                           coefi, feats);
            mlp_kernel<<<N_PTS / 256, 256, 0, stream>>>(feats, nullptr, wt, biases,
                                                        (float*)d_out);
        }
    } else {
        feat_s_kernel<<<N_PTS / 256, 256, 0, stream>>>(x, g0, g1, g2, g3, coef,
                                                       feats);
        mlp_kernel<<<N_PTS / 256, 256, 0, stream>>>(feats, nullptr, wt, biases,
                                                    (float*)d_out);
    }
}

// Round 9
// 713.369 us; speedup vs baseline: 1.0779x; 1.0172x over previous
//
#include <hip/hip_runtime.h>
#include <hip/hip_fp16.h>

#define N_PTS 524288
#define NBUCK 1024
#define SBLK 1024               // points per sort block
#define NSBLK (N_PTS / SBLK)    // 512

typedef __attribute__((ext_vector_type(8))) short bf16x8;
typedef __attribute__((ext_vector_type(4))) short bf16x4;
typedef __attribute__((ext_vector_type(4))) float f32x4;
typedef __attribute__((ext_vector_type(4))) unsigned int u32x4;

// float -> bf16 (round-to-nearest-even), bit pattern in ushort
__device__ __forceinline__ unsigned short f2bf(float f) {
    unsigned u = __builtin_bit_cast(unsigned, f);
    u = (u + 0x7FFFu + ((u >> 16) & 1u)) >> 16;
    return (unsigned short)u;
}

// packed RNE f32x2 -> bf16x2 (low=a, high=b) — native gfx950 instr; same RNE
// rounding as f2bf but 1 VALU op instead of ~8.
__device__ __forceinline__ unsigned cvtpk_bf16(float a, float b) {
    unsigned r;
    asm("v_cvt_pk_bf16_f32 %0, %1, %2" : "=v"(r) : "v"(a), "v"(b));
    return r;
}

__device__ __forceinline__ float encf(float v, float f) {
    float t = v * f;
    return 2.0f * (t - floorf(t)) - 1.0f;   // jnp: 2*(f*x % 1) - 1
}

// spatial bucket key: top bits of the g3 (256^3, freq-8) integer coords.
// 10 bits: (iz>>4)<<6 | (iy>>5)<<3 | (ix>>5). Must be identical in hist/scatter.
__device__ __forceinline__ int bucket_of(float px, float py, float pz) {
    float cx = (encf(px, 8.f) + 1.0f) * 127.5f;
    float cy = (encf(py, 8.f) + 1.0f) * 127.5f;
    float cz = (encf(pz, 8.f) + 1.0f) * 127.5f;
    int ix = min(max((int)floorf(cx), 0), 255);
    int iy = min(max((int)floorf(cy), 0), 255);
    int iz = min(max((int)floorf(cz), 0), 255);
    return ((iz >> 4) << 6) | ((iy >> 5) << 3) | (ix >> 5);
}

// ---------------- sort pass kernels (ZERO global atomics) ----------------
// pass 1: per-block LDS histogram -> hist2d[blk][NBUCK] (coalesced)
__global__ __launch_bounds__(256) void hist2_kernel(const float* __restrict__ x,
                                                    unsigned* __restrict__ hist2d) {
    __shared__ unsigned lh[NBUCK];
    int t = threadIdx.x;
    int blk = blockIdx.x;
#pragma unroll
    for (int i = 0; i < 4; ++i) lh[t + i * 256] = 0u;
    __syncthreads();
#pragma unroll
    for (int i = 0; i < 4; ++i) {
        int gid = blk * SBLK + i * 256 + t;
        atomicAdd(&lh[bucket_of(x[3 * gid], x[3 * gid + 1], x[3 * gid + 2])], 1u);
    }
    __syncthreads();
#pragma unroll
    for (int i = 0; i < 4; ++i)
        hist2d[(size_t)blk * NBUCK + t + i * 256] = lh[t + i * 256];
}

// pass 2: per-bucket scan over the 512 block counts (1 wave per bucket).
// start2d[blk][j] = # of bucket-j points in blocks < blk; totals[j] = count.
__global__ __launch_bounds__(64) void scanb_kernel(const unsigned* __restrict__ hist2d,
                                                   unsigned* __restrict__ start2d,
                                                   unsigned* __restrict__ totals) {
    int j = blockIdx.x;         // bucket
    int lane = threadIdx.x;     // 0..63, covers blocks [lane*8, lane*8+8)
    int b0 = lane * 8;
    unsigned c[8];
#pragma unroll
    for (int k = 0; k < 8; ++k) c[k] = hist2d[(size_t)(b0 + k) * NBUCK + j];
    unsigned s = 0;
#pragma unroll
    for (int k = 0; k < 8; ++k) s += c[k];
    // wave-exclusive scan of s across 64 lanes
    unsigned v = s;
    for (int off = 1; off < 64; off <<= 1) {
        unsigned u = __shfl_up(v, off, 64);
        if (lane >= off) v += u;
    }
    unsigned run = v - s;       // exclusive prefix
#pragma unroll
    for (int k = 0; k < 8; ++k) {
        start2d[(size_t)(b0 + k) * NBUCK + j] = run;
        run += c[k];
    }
    if (lane == 63) totals[j] = run;
}

// pass 3: exclusive scan of bucket totals -> bucketBase
__global__ __launch_bounds__(1024) void scan_kernel(const unsigned* __restrict__ totals,
                                                    unsigned* __restrict__ bucketBase) {
    __shared__ unsigned s[NBUCK];
    int t = threadIdx.x;
    unsigned mine = totals[t];
    s[t] = mine;
    __syncthreads();
    for (int off = 1; off < NBUCK; off <<= 1) {
        unsigned v = (t >= off) ? s[t - off] : 0u;
        __syncthreads();
        s[t] += v;
        __syncthreads();
    }
    bucketBase[t] = s[t] - mine;   // exclusive prefix
}

// pass 4: deterministic scatter; local rank via LDS atomics only.
__global__ __launch_bounds__(256) void scatter2_kernel(
    const float* __restrict__ x,
    const unsigned* __restrict__ start2d,
    const unsigned* __restrict__ bucketBase,
    float4* __restrict__ rec, int* __restrict__ invPos) {
    __shared__ unsigned lc[NBUCK];
    int t = threadIdx.x;
    int blk = blockIdx.x;
#pragma unroll
    for (int i = 0; i < 4; ++i) lc[t + i * 256] = 0u;
    __syncthreads();
#pragma unroll
    for (int i = 0; i < 4; ++i) {
        int gid = blk * SBLK + i * 256 + t;
        float px = x[3 * gid], py = x[3 * gid + 1], pz = x[3 * gid + 2];
        int b = bucket_of(px, py, pz);
        unsigned lrank = atomicAdd(&lc[b], 1u);   // LDS atomic: cheap
        unsigned pos = bucketBase[b] + start2d[(size_t)blk * NBUCK + b] + lrank;
        rec[pos] = make_float4(px, py, pz, 0.0f);
        invPos[gid] = (int)pos;
    }
}

// ---------------- channel-interleave to fp16: [4][R^3] -> [R^3][4] ----------------
template <int R>
__global__ __launch_bounds__(256) void ileaveh_kernel(const float* __restrict__ g,
                                                      unsigned short* __restrict__ gi) {
    constexpr int V = R * R * R;
    int idx = blockIdx.x * 256 + threadIdx.x;
    ushort4 v;
    v.x = __half_as_ushort(__float2half(g[idx]));
    v.y = __half_as_ushort(__float2half(g[idx + V]));
    v.z = __half_as_ushort(__float2half(g[idx + 2 * V]));
    v.w = __half_as_ushort(__float2half(g[idx + 3 * V]));
    *(ushort4*)(&gi[(size_t)idx * 4]) = v;
}

__device__ __forceinline__ float4 h4fu(uint2 u) {
    float4 r;
    r.x = __half2float(__ushort_as_half((unsigned short)(u.x & 0xffffu)));
    r.y = __half2float(__ushort_as_half((unsigned short)(u.x >> 16)));
    r.z = __half2float(__ushort_as_half((unsigned short)(u.y & 0xffffu)));
    r.w = __half2float(__ushort_as_half((unsigned short)(u.y >> 16)));
    return r;
}

// ---- phase-split trilerp: setup (addresses+weights) / load (8x8B) / combine ----
struct TriCtx {
    const unsigned short* p;   // base corner pointer (4 ch fp16)
    int dx, dy, dz;            // neighbor offsets in ushorts (0 at edge)
    float fx, fy, fz;          // lerp fractions
};

template <int R>
__device__ __forceinline__ TriCtx tri_setup(const unsigned short* __restrict__ gi,
                                            float px, float py, float pz) {
    constexpr float S = 0.5f * (float)(R - 1);
    float cx = (px + 1.0f) * S;
    float cy = (py + 1.0f) * S;
    float cz = (pz + 1.0f) * S;
    float fx0 = floorf(cx), fy0 = floorf(cy), fz0 = floorf(cz);
    TriCtx c;
    c.fx = cx - fx0; c.fy = cy - fy0; c.fz = cz - fz0;
    int ix0 = min(max((int)fx0, 0), R - 1);
    int iy0 = min(max((int)fy0, 0), R - 1);
    int iz0 = min(max((int)fz0, 0), R - 1);
    c.dx = (ix0 < R - 1) ? 4 : 0;
    c.dy = (iy0 < R - 1) ? 4 * R : 0;
    c.dz = (iz0 < R - 1) ? 4 * R * R : 0;
    c.p = gi + 4 * ((size_t)iz0 * (R * R) + iy0 * R + ix0);
    return c;
}

__device__ __forceinline__ void tri_load(const TriCtx& c, uint2* L) {
    L[0] = *(const uint2*)(c.p);
    L[1] = *(const uint2*)(c.p + c.dx);
    L[2] = *(const uint2*)(c.p + c.dy);
    L[3] = *(const uint2*)(c.p + c.dy + c.dx);
    L[4] = *(const uint2*)(c.p + c.dz);
    L[5] = *(const uint2*)(c.p + c.dz + c.dx);
    L[6] = *(const uint2*)(c.p + c.dz + c.dy);
    L[7] = *(const uint2*)(c.p + c.dz + c.dy + c.dx);
}

__device__ __forceinline__ float4 tri_combine(const TriCtx& c, const uint2* L) {
    float4 v000 = h4fu(L[0]);
    float4 v001 = h4fu(L[1]);
    float4 v010 = h4fu(L[2]);
    float4 v011 = h4fu(L[3]);
    float4 v100 = h4fu(L[4]);
    float4 v101 = h4fu(L[5]);
    float4 v110 = h4fu(L[6]);
    float4 v111 = h4fu(L[7]);

    float gx0 = 1.0f - c.fx, gy0 = 1.0f - c.fy, gz0 = 1.0f - c.fz;
    float w00 = gz0 * gy0, w01 = gz0 * c.fy, w10 = c.fz * gy0, w11 = c.fz * c.fy;
    float w000 = w00 * gx0, w001 = w00 * c.fx;
    float w010 = w01 * gx0, w011 = w01 * c.fx;
    float w100 = w10 * gx0, w101 = w10 * c.fx;
    float w110 = w11 * gx0, w111 = w11 * c.fx;

    float4 r;
    r.x = v000.x * w000 + v001.x * w001 + v010.x * w010 + v011.x * w011 +
          v100.x * w100 + v101.x * w101 + v110.x * w110 + v111.x * w111;
    r.y = v000.y * w000 + v001.y * w001 + v010.y * w010 + v011.y * w011 +
          v100.y * w100 + v101.y * w101 + v110.y * w110 + v111.y * w111;
    r.z = v000.z * w000 + v001.z * w001 + v010.z * w010 + v011.z * w011 +
          v100.z * w100 + v101.z * w101 + v110.z * w110 + v111.z * w111;
    r.w = v000.w * w000 + v001.w * w001 + v010.w * w010 + v011.w * w011 +
          v100.w * w100 + v101.w * w101 + v110.w * w110 + v111.w * w111;
    return r;
}

// strided (original-layout fp32) trilerp — fallback path only
template <int R>
__device__ __forceinline__ float4 trilerp4s(const float* __restrict__ g,
                                            float px, float py, float pz) {
    constexpr float S = 0.5f * (float)(R - 1);
    float cx = (px + 1.0f) * S;
    float cy = (py + 1.0f) * S;
    float cz = (pz + 1.0f) * S;
    float fx0 = floorf(cx), fy0 = floorf(cy), fz0 = floorf(cz);
    float fx = cx - fx0, fy = cy - fy0, fz = cz - fz0;
    int ix0 = min(max((int)fx0, 0), R - 1);
    int iy0 = min(max((int)fy0, 0), R - 1);
    int iz0 = min(max((int)fz0, 0), R - 1);
    int dx = (ix0 < R - 1) ? 1 : 0;
    int dy = (iy0 < R - 1) ? R : 0;
    int dz = (iz0 < R - 1) ? R * R : 0;
    int base = iz0 * (R * R) + iy0 * R + ix0;

    float gx0 = 1.0f - fx, gy0 = 1.0f - fy, gz0 = 1.0f - fz;
    float w00 = gz0 * gy0, w01 = gz0 * fy, w10 = fz * gy0, w11 = fz * fy;
    float w000 = w00 * gx0, w001 = w00 * fx;
    float w010 = w01 * gx0, w011 = w01 * fx;
    float w100 = w10 * gx0, w101 = w10 * fx;
    float w110 = w11 * gx0, w111 = w11 * fx;

    float4 out;
    float r[4];
#pragma unroll
    for (int c = 0; c < 4; ++c) {
        const float* gc = g + (size_t)c * (R * R * R);
        r[c] = gc[base] * w000 + gc[base + dx] * w001 + gc[base + dy] * w010 +
               gc[base + dy + dx] * w011 + gc[base + dz] * w100 +
               gc[base + dz + dx] * w101 + gc[base + dz + dy] * w110 +
               gc[base + dz + dy + dx] * w111;
    }
    out.x = r[0]; out.y = r[1]; out.z = r[2]; out.w = r[3];
    return out;
}

// shared feature math, phase-split: ALL 40 corner loads are issued before any
// lerp math (g3/g2 — the HBM/L3-latency grids — first). One point = one memory
// round-trip instead of ~5 serial ones. Values identical to the fused version.
__device__ __forceinline__ void feat_core(
    float px, float py, float pz,
    const unsigned short* __restrict__ g0i, const unsigned short* __restrict__ g1i,
    const unsigned short* __restrict__ g2i, const unsigned short* __restrict__ g3i,
    const unsigned short* __restrict__ coefi,
    unsigned short* __restrict__ feats, size_t i) {
    // phase 1: addresses + weights for all 5 trilerps
    TriCtx c3 = tri_setup<256>(g3i, encf(px, 8.f), encf(py, 8.f), encf(pz, 8.f));
    TriCtx c2 = tri_setup<128>(g2i, encf(px, 4.f), encf(py, 4.f), encf(pz, 4.f));
    TriCtx c1 = tri_setup<64>(g1i, encf(px, 2.f), encf(py, 2.f), encf(pz, 2.f));
    TriCtx c0 = tri_setup<32>(g0i, encf(px, 1.f), encf(py, 1.f), encf(pz, 1.f));
    TriCtx cc = tri_setup<64>(coefi, px, py, pz);

    // phase 2: issue all 40 loads (highest-latency grids first)
    uint2 L3[8], L2[8], L1[8], L0[8], LC[8];
    tri_load(c3, L3);
    tri_load(c2, L2);
    tri_load(c1, L1);
    tri_load(c0, L0);
    tri_load(cc, LC);

    // phase 3: math (small grids' loads return first)
    float4 cf = tri_combine(cc, LC);
    float4 t0 = tri_combine(c0, L0);
    float4 t1 = tri_combine(c1, L1);
    float4 t2 = tri_combine(c2, L2);
    float4 t3 = tri_combine(c3, L3);

    float o[16];
    o[0] = t0.x * cf.x; o[1] = t0.y * cf.x; o[2] = t0.z * cf.x; o[3] = t0.w * cf.x;
    o[4] = t1.x * cf.y; o[5] = t1.y * cf.y; o[6] = t1.z * cf.y; o[7] = t1.w * cf.y;
    o[8] = t2.x * cf.z; o[9] = t2.y * cf.z; o[10] = t2.z * cf.z; o[11] = t2.w * cf.z;
    o[12] = t3.x * cf.w; o[13] = t3.y * cf.w; o[14] = t3.z * cf.w; o[15] = t3.w * cf.w;

    bf16x8 lo, hi;
#pragma unroll
    for (int j = 0; j < 8; ++j) {
        lo[j] = (short)f2bf(o[j]);
        hi[j] = (short)f2bf(o[8 + j]);
    }
    bf16x8* dst = (bf16x8*)(feats + i * 16);
    dst[0] = lo;
    dst[1] = hi;
}

// ---------------- kernel 1a: features from SORTED records (1 pt/thread) --------
__global__ __launch_bounds__(256) void feat_sorted_kernel(
    const float4* __restrict__ rec,
    const unsigned short* __restrict__ g0i, const unsigned short* __restrict__ g1i,
    const unsigned short* __restrict__ g2i, const unsigned short* __restrict__ g3i,
    const unsigned short* __restrict__ coefi,
    unsigned short* __restrict__ feats) {
    int i = blockIdx.x * 256 + threadIdx.x;
    float4 r = rec[i];
    feat_core(r.x, r.y, r.z, g0i, g1i, g2i, g3i, coefi, feats, (size_t)i);
}

// ---------------- kernel 1b: features in original order (no sort) ----------------
__global__ __launch_bounds__(256) void feat_i_kernel(
    const float* __restrict__ x,
    const unsigned short* __restrict__ g0i, const unsigned short* __restrict__ g1i,
    const unsigned short* __restrict__ g2i, const unsigned short* __restrict__ g3i,
    const unsigned short* __restrict__ coefi,
    unsigned short* __restrict__ feats) {
    int i = blockIdx.x * 256 + threadIdx.x;
    feat_core(x[3 * i], x[3 * i + 1], x[3 * i + 2], g0i, g1i, g2i, g3i, coefi,
              feats, (size_t)i);
}

// fallback (workspace too small for interleaved grids)
__global__ __launch_bounds__(256) void feat_s_kernel(
    const float* __restrict__ x,
    const float* __restrict__ g0, const float* __restrict__ g1,
    const float* __restrict__ g2, const float* __restrict__ g3,
    const float* __restrict__ coef,
    unsigned short* __restrict__ feats) {
    int i = blockIdx.x * 256 + threadIdx.x;
    float px = x[3 * i + 0], py = x[3 * i + 1], pz = x[3 * i + 2];

    float4 cf = trilerp4s<64>(coef, px, py, pz);
    float4 t0 = trilerp4s<32>(g0, encf(px, 1.f), encf(py, 1.f), encf(pz, 1.f));
    float4 t1 = trilerp4s<64>(g1, encf(px, 2.f), encf(py, 2.f), encf(pz, 2.f));
    float4 t2 = trilerp4s<128>(g2, encf(px, 4.f), encf(py, 4.f), encf(pz, 4.f));
    float4 t3 = trilerp4s<256>(g3, encf(px, 8.f), encf(py, 8.f), encf(pz, 8.f));

    float o[16];
    o[0] = t0.x * cf.x; o[1] = t0.y * cf.x; o[2] = t0.z * cf.x; o[3] = t0.w * cf.x;
    o[4] = t1.x * cf.y; o[5] = t1.y * cf.y; o[6] = t1.z * cf.y; o[7] = t1.w * cf.y;
    o[8] = t2.x * cf.z; o[9] = t2.y * cf.z; o[10] = t2.z * cf.z; o[11] = t2.w * cf.z;
    o[12] = t3.x * cf.w; o[13] = t3.y * cf.w; o[14] = t3.z * cf.w; o[15] = t3.w * cf.w;

    bf16x8 lo, hi;
#pragma unroll
    for (int j = 0; j < 8; ++j) {
        lo[j] = (short)f2bf(o[j]);
        hi[j] = (short)f2bf(o[8 + j]);
    }
    bf16x8* dst = (bf16x8*)(feats + (size_t)i * 16);
    dst[0] = lo;
    dst[1] = hi;
}

// ---------------- kernel 2: weight prep -> MFMA-fragment order ----------------
// (unchanged — layout verified by bit-identical absmax)
__global__ __launch_bounds__(256) void prep_kernel(
    const float* __restrict__ W0, const float* __restrict__ W1,
    const float* __restrict__ W2, const float* __restrict__ W3,
    const float* __restrict__ W4, const float* __restrict__ W5,
    const float* __restrict__ W6,
    const float* __restrict__ B0, const float* __restrict__ B1,
    const float* __restrict__ B2, const float* __restrict__ B3,
    const float* __restrict__ B4, const float* __restrict__ B5,
    const float* __restrict__ B6,
    unsigned short* __restrict__ wt, float* __restrict__ biases) {
    int tid = blockIdx.x * 256 + threadIdx.x;
    if (tid < 102400) {
        int l, e;
        if (tid < 4096) { l = 0; e = tid; }
        else { l = 1 + (tid - 4096) / 16384; e = (tid - 4096) & 16383; }
        int j = e & 7;
        int lane = (e >> 3) & 63;
        int ni = (e >> 9) & 7;
        int kk = (e >> 12) & 3;
        int lr = lane & 15;
        int q = lane >> 4;
        int n = ni * 16 + lr;
        const float* W = (l == 0) ? W0 : (l == 1) ? W1 : (l == 2) ? W2
                        : (l == 3) ? W3 : (l == 4) ? W4 : (l == 5) ? W5 : W6;
        float v;
        if (l == 0) {
            int k = q * 8 + j;
            v = (k < 16) ? W[k * 128 + n] : 0.0f;
        } else {
            int h = (2 * kk + (j >> 2)) * 16 + q * 4 + (j & 3);
            v = W[h * 128 + n];
        }
        wt[tid] = f2bf(v);
    } else if (tid < 102400 + 896) {
        int e = tid - 102400;
        int l = e >> 7;
        const float* B = (l == 0) ? B0 : (l == 1) ? B1 : (l == 2) ? B2
                        : (l == 3) ? B3 : (l == 4) ? B4 : (l == 5) ? B5 : B6;
        biases[e] = B[e & 127];
    }
}

// ---------------- kernel 3: fused 7-layer MLP (round-8 version, unchanged) ----
// 4 waves x 64 rows; register-local pi-transition; double-buffered LDS weight
// staging; v_cvt_pk_bf16_f32 repack.
#define WBUF 16640  // shorts per buffer (16384 weight shorts + 256 shorts of fp32 bias)

__device__ __forceinline__ void stage16(const unsigned short* __restrict__ gsrc,
                                        unsigned short* lbase) {
    __builtin_amdgcn_global_load_lds(
        (const __attribute__((address_space(1))) void*)gsrc,
        (__attribute__((address_space(3))) void*)lbase, 16, 0, 0);
}

__global__ __launch_bounds__(256, 2) void mlp_kernel(
    const unsigned short* __restrict__ feats,
    const int* __restrict__ invPos,
    const unsigned short* __restrict__ wt,
    const float* __restrict__ biases,
    float* __restrict__ out) {
    __shared__ __attribute__((aligned(16))) unsigned short Wlds[2 * WBUF];

    const int t = threadIdx.x;
    const int lane = t & 63;
    const int w = t >> 6;
    const int lr = lane & 15;
    const int q = lane >> 4;
    const size_t rowq = (size_t)blockIdx.x * 256 + w * 64;  // wave's first row

    // ---- prologue: stage layer-0 weights (8KB) + bias0; load H0 frags ----
    {
#pragma unroll
        for (int i = 0; i < 2; ++i) {
            int idx = i * 4 + w;                    // wave-chunk 0..7
            stage16(wt + idx * 512 + lane * 8, Wlds + idx * 512);
        }
        if (t < 128) ((float*)(Wlds + 16384))[t] = biases[t];
    }

    bf16x8 h0[4];
#pragma unroll
    for (int mi = 0; mi < 4; ++mi) {
        size_t r = rowq + mi * 16 + lr;
        size_t p = invPos ? (size_t)invPos[r] : r;
        if (q < 2)
            h0[mi] = *(const bf16x8*)(feats + p * 16 + q * 8);
        else
            h0[mi] = (bf16x8)0;
    }
    __syncthreads();   // buf0 (L0) ready

    f32x4 acc[4][8];

    // ---- layer 0: K=16 (padded to 32) ----
    {
        const unsigned short* w1 = wt + 4096;
#pragma unroll
        for (int i = 0; i < 8; ++i) {
            int idx = i * 4 + w;                    // 0..31
            stage16(w1 + idx * 512 + lane * 8, Wlds + WBUF + idx * 512);
        }
        if (t < 128) ((float*)(Wlds + WBUF + 16384))[t] = biases[128 + t];

        const unsigned short* cw = Wlds;
        const float* cb = (const float*)(Wlds + 16384);
#pragma unroll
        for (int ni = 0; ni < 8; ++ni) {
            f32x4 bv = *(const f32x4*)(cb + ni * 16 + q * 4);
#pragma unroll
            for (int mi = 0; mi < 4; ++mi) acc[mi][ni] = bv;
        }
#pragma unroll
        for (int ni = 0; ni < 8; ++ni) {
            bf16x8 wf = *(const bf16x8*)(cw + (ni * 64 + lane) * 8);
#pragma unroll
            for (int mi = 0; mi < 4; ++mi)
                acc[mi][ni] = __builtin_amdgcn_mfma_f32_16x16x32_bf16(
                    wf, h0[mi], acc[mi][ni], 0, 0, 0);
        }
        __syncthreads();  // drains staging vmcnt -> buf1 ready; buf0 reads done
    }

    // ---- layers 1..6 ----
    bf16x8 hf[4][4];
    for (int l = 1; l < 7; ++l) {
        unsigned short* cwm = Wlds + (l & 1) * WBUF;
        if (l < 6) {
            const unsigned short* wn = wt + 4096 + l * 16384;
            unsigned short* nb = Wlds + ((l + 1) & 1) * WBUF;
#pragma unroll
            for (int i = 0; i < 8; ++i) {
                int idx = i * 4 + w;
                stage16(wn + idx * 512 + lane * 8, nb + idx * 512);
            }
            if (t < 128) ((float*)(nb + 16384))[t] = biases[(l + 1) * 128 + t];
        }

        // acc (bias included) -> relu -> bf16 B-frags, register-local (pi in wt).
        // Word w2 of hf[mi][kk] holds elements jp=2*w2 (low) and 2*w2+1 (high):
        //   jp>>2 == w2>>1, jp&3 == (w2&1)*2 (+1 for high) — packed convert.
#pragma unroll
        for (int mi = 0; mi < 4; ++mi)
#pragma unroll
            for (int kk = 0; kk < 4; ++kk) {
                u32x4 wv;
#pragma unroll
                for (int w2 = 0; w2 < 4; ++w2) {
                    float a = fmaxf(acc[mi][2 * kk + (w2 >> 1)][(w2 & 1) * 2], 0.0f);
                    float b = fmaxf(acc[mi][2 * kk + (w2 >> 1)][(w2 & 1) * 2 + 1], 0.0f);
                    wv[w2] = cvtpk_bf16(a, b);
                }
                hf[mi][kk] = __builtin_bit_cast(bf16x8, wv);
            }
        const float* cb = (const float*)(cwm + 16384);
#pragma unroll
        for (int ni = 0; ni < 8; ++ni) {
            f32x4 bv = *(const f32x4*)(cb + ni * 16 + q * 4);
#pragma unroll
            for (int mi = 0; mi < 4; ++mi) acc[mi][ni] = bv;
        }
#pragma unroll
        for (int kk = 0; kk < 4; ++kk) {
            bf16x8 wf[8];
#pragma unroll
            for (int ni = 0; ni < 8; ++ni)
                wf[ni] = *(const bf16x8*)(cwm + ((kk * 8 + ni) * 64 + lane) * 8);
#pragma unroll
            for (int ni = 0; ni < 8; ++ni)
#pragma unroll
                for (int mi = 0; mi < 4; ++mi)
                    acc[mi][ni] = __builtin_amdgcn_mfma_f32_16x16x32_bf16(
                        wf[ni], hf[mi][kk], acc[mi][ni], 0, 0, 0);
        }
        if (l < 6) __syncthreads();
    }

    // ---- epilogue: layer 6 has no relu; bias already in acc ----
#pragma unroll
    for (int mi = 0; mi < 4; ++mi)
#pragma unroll
        for (int ni = 0; ni < 8; ++ni) {
            *(f32x4*)(&out[(rowq + mi * 16 + lr) * 128 + ni * 16 + q * 4]) =
                acc[mi][ni];
        }
}

extern "C" void kernel_launch(void* const* d_in, const int* in_sizes, int n_in,
                              void* d_out, int out_size, void* d_ws, size_t ws_size,
                              hipStream_t stream) {
    const float* x = (const float*)d_in[0];
    const float* g0 = (const float*)d_in[1];
    const float* g1 = (const float*)d_in[2];
    const float* g2 = (const float*)d_in[3];
    const float* g3 = (const float*)d_in[4];
    const float* coef = (const float*)d_in[5];
    const float* W[7];
    const float* B[7];
    for (int j = 0; j < 7; ++j) {
        W[j] = (const float*)d_in[6 + 2 * j];
        B[j] = (const float*)d_in[7 + 2 * j];
    }

    // workspace layout (bytes), fp16 interleaved grids + atomic-free sort:
    //   feats      @ 0          16,777,216   (bf16 [N][16], SORTED order on fast2)
    //   wt         @ 16777216      204,800   (bf16 fragment-order weights)
    //   biases     @ 16982016        3,584   (fp32 [7][128])
    //   coefi      @ 16985600    2,097,152   (fp16 [64^3][4])
    //   g0i        @ 19082752      262,144
    //   g1i        @ 19344896    2,097,152
    //   g2i        @ 21442048   16,777,216   -> 38,219,264
    //   hist2d     @ 38219264    2,097,152   (u32 [512][1024])
    //   start2d    @ 40316416    2,097,152   (u32 [512][1024])
    //   totals     @ 42413568        4,096
    //   bucketBase @ 42417664        4,096
    //   rec        @ 42421760    8,388,608   (float4 sorted points)
    //   invPos     @ 50810368    2,097,152   -> end 52,907,520
    // g3i (fp16 [256^3][4] = 134,217,728 B) aliases d_out (out is 268 MB),
    // safe: ileave -> feat(read) -> mlp(write) are stream-ordered.
    char* ws = (char*)d_ws;
    unsigned short* feats = (unsigned short*)ws;
    unsigned short* wt = (unsigned short*)(ws + 16777216);
    float* biases = (float*)(ws + 16982016);
    unsigned short* coefi = (unsigned short*)(ws + 16985600);
    unsigned short* g0i = (unsigned short*)(ws + 19082752);
    unsigned short* g1i = (unsigned short*)(ws + 19344896);
    unsigned short* g2i = (unsigned short*)(ws + 21442048);
    unsigned* hist2d = (unsigned*)(ws + 38219264);
    unsigned* start2d = (unsigned*)(ws + 40316416);
    unsigned* totals = (unsigned*)(ws + 42413568);
    unsigned* bucketBase = (unsigned*)(ws + 42417664);
    float4* rec = (float4*)(ws + 42421760);
    int* invPos = (int*)(ws + 50810368);
    unsigned short* g3i = (unsigned short*)d_out;

    prep_kernel<<<404, 256, 0, stream>>>(W[0], W[1], W[2], W[3], W[4], W[5], W[6],
                                         B[0], B[1], B[2], B[3], B[4], B[5], B[6],
                                         wt, biases);

    bool fast = ws_size >= 38219264ull;
    bool fast2 = ws_size >= 52907520ull;
    if (fast) {
        ileaveh_kernel<64><<<1024, 256, 0, stream>>>(coef, coefi);
        ileaveh_kernel<32><<<128, 256, 0, stream>>>(g0, g0i);
        ileaveh_kernel<64><<<1024, 256, 0, stream>>>(g1, g1i);
        ileaveh_kernel<128><<<8192, 256, 0, stream>>>(g2, g2i);
        ileaveh_kernel<256><<<65536, 256, 0, stream>>>(g3, g3i);
        if (fast2) {
            hist2_kernel<<<NSBLK, 256, 0, stream>>>(x, hist2d);
            scanb_kernel<<<NBUCK, 64, 0, stream>>>(hist2d, start2d, totals);
            scan_kernel<<<1, 1024, 0, stream>>>(totals, bucketBase);
            scatter2_kernel<<<NSBLK, 256, 0, stream>>>(x, start2d, bucketBase,
                                                       rec, invPos);
            feat_sorted_kernel<<<N_PTS / 256, 256, 0, stream>>>(rec, g0i, g1i, g2i,
                                                                g3i, coefi, feats);
            mlp_kernel<<<N_PTS / 256, 256, 0, stream>>>(feats, invPos, wt, biases,
                                                        (float*)d_out);
        } else {
            feat_i_kernel<<<N_PTS / 256, 256, 0, stream>>>(x, g0i, g1i, g2i, g3i,
                                                           coefi, feats);
            mlp_kernel<<<N_PTS / 256, 256, 0, stream>>>(feats, nullptr, wt, biases,
                                                        (float*)d_out);
        }
    } else {
        feat_s_kernel<<<N_PTS / 256, 256, 0, stream>>>(x, g0, g1, g2, g3, coef,
                                                       feats);
        mlp_kernel<<<N_PTS / 256, 256, 0, stream>>>(feats, nullptr, wt, biases,
                                                    (float*)d_out);
    }
}